// Round 10
// baseline (492.274 us; speedup 1.0000x reference)
//
#include <hip/hip_runtime.h>
#include <hip/hip_bf16.h>
#include <hip/hip_fp16.h>

#define B2F(x) __bfloat162float(x)
#define F2B(x) __float2bfloat16(x)

typedef __bf16 bf16x8 __attribute__((ext_vector_type(8)));
typedef float floatx4 __attribute__((ext_vector_type(4)));

static constexpr int MROWS = 50176;   // 512 windows * 98 tokens
static constexpr int CDIM  = 256;

enum { MODE_BF16 = 0, MODE_VALOFFAW = 1, MODE_REVERSE = 3, MODE_ATTN = 6 };

#if defined(__has_builtin)
#if __has_builtin(__builtin_amdgcn_global_load_lds)
#define HAS_GLL 1
#endif
#endif
#ifndef HAS_GLL
#define HAS_GLL 0
#endif

// ---------------- helpers ----------------

__device__ __forceinline__ void win_decode(int r, int& tok) {
    int w = r / 98, n = r - w * 98;
    int dB = w >> 6, hB = (w >> 3) & 7, wB = w & 7;
    int z = n / 49, n2 = n - z * 49, yy = n2 / 7, xx = n2 - yy * 7;
    tok = ((dB * 2 + z) * 56 + hB * 7 + yy) * 56 + wB * 7 + xx;
}

__device__ __forceinline__ float bf2f(unsigned short u) {
    return __uint_as_float(((unsigned)u) << 16);
}

__device__ __forceinline__ float wave_sum64(float v) {
#pragma unroll
    for (int off = 32; off > 0; off >>= 1) v += __shfl_xor(v, off, 64);
    return v;
}

// ---------------- fused front: weight transpose + diag/csum + LN1 (one launch) ----------------
// LN1 arm: 4 rows per wave (loads batched up front for MLP/ILP).

__global__ __launch_bounds__(256) void fused_pre(
    const float* __restrict__ x, const float* __restrict__ n1g, const float* __restrict__ n1b,
    __hip_bfloat16* __restrict__ xw,
    const float* __restrict__ mask, float* __restrict__ diag, float* __restrict__ csum,
    const float* __restrict__ val_w, const float* __restrict__ off_w,
    const float* __restrict__ aw_w,  const float* __restrict__ out_w,
    const float* __restrict__ proj_w, const float* __restrict__ fc1_w,
    const float* __restrict__ fc2_w,
    __hip_bfloat16* __restrict__ valT, __hip_bfloat16* __restrict__ offawT,
    __hip_bfloat16* __restrict__ outT, __hip_bfloat16* __restrict__ projT,
    __hip_bfloat16* __restrict__ fc1T, __hip_bfloat16* __restrict__ fc2T) {
    const int bid = blockIdx.x;
    const int tid = threadIdx.x;

    if (bid < 2944) {   // ---- transpose ----
        const float* src; __hip_bfloat16* dst; int K, N, base;
        if (bid < 256)       { src = val_w;  dst = valT;            K = 256;  N = 256;  base = 0; }
        else if (bid < 352)  { src = off_w;  dst = offawT;          K = 256;  N = 96;   base = 256; }
        else if (bid < 384)  { src = aw_w;   dst = offawT + 96*256; K = 256;  N = 32;   base = 352; }
        else if (bid < 640)  { src = out_w;  dst = outT;            K = 256;  N = 256;  base = 384; }
        else if (bid < 896)  { src = proj_w; dst = projT;           K = 256;  N = 256;  base = 640; }
        else if (bid < 1920) { src = fc1_w;  dst = fc1T;            K = 256;  N = 1024; base = 896; }
        else                 { src = fc2_w;  dst = fc2T;            K = 1024; N = 256;  base = 1920; }
        int i = (bid - base) * 256 + tid;
        if (i >= K * N) return;
        int nn = i / K, kk = i - nn * K;
        dst[(size_t)nn * K + kk] = F2B(src[(size_t)kk * N + nn]);
    } else if (bid < 3140) {   // ---- diag ----
        int r = (bid - 2944) * 256 + tid;
        int n = r % 98;
        int z = n / 49, n2 = n - z * 49, yy = n2 / 7, xx = n2 - yy * 7;
        const float* mb = mask + (size_t)r * 98;
        float m = mb[z * 49 + yy * 7 + xx];
        float sz = 0.f, sy = 0.f, sx = 0.f;
        for (int k = 0; k <= z; ++k)  sz += mb[k * 49 + yy * 7 + xx];
        for (int k = 0; k <= yy; ++k) sy += mb[z * 49 + k * 7 + xx];
        for (int k = 0; k <= xx; ++k) sx += mb[z * 49 + yy * 7 + k];
        const float PI = 3.14159265358979323846f;
        diag[r] = m * (sinf(sx * m / PI) + sinf(sy * m) + sz * m / PI);
    } else if (bid == 3140) {  // ---- csum (column sums of f32 weights) ----
        if (tid < 96) {
            float s = 0.f;
            for (int k = 0; k < 256; ++k) s += off_w[(size_t)k * 96 + tid];
            csum[tid] = s;
        } else if (tid < 128) {
            int n = tid - 96;
            float s = 0.f;
            for (int k = 0; k < 256; ++k) s += aw_w[(size_t)k * 32 + n];
            csum[tid] = s;
        }
    } else {                   // ---- LN1, 4 rows per wave ----
        const int lane = tid & 63;
        const int rb = (bid - 3141) * 16 + (tid >> 6) * 4;
        const int c0 = lane * 4;
        float4 v[4];
#pragma unroll
        for (int k = 0; k < 4; ++k) {
            int tok; win_decode(rb + k, tok);
            v[k] = *(const float4*)(x + (size_t)tok * CDIM + c0);
        }
        float4 gg = *(const float4*)(n1g + c0);
        float4 bb = *(const float4*)(n1b + c0);
#pragma unroll
        for (int k = 0; k < 4; ++k) {
            float mean = wave_sum64(v[k].x + v[k].y + v[k].z + v[k].w) * (1.f / 256.f);
            float dx = v[k].x - mean, dy = v[k].y - mean, dz = v[k].z - mean, dw = v[k].w - mean;
            float var = wave_sum64(dx * dx + dy * dy + dz * dz + dw * dw) * (1.f / 256.f);
            float rstd = rsqrtf(var + 1e-5f);
            __hip_bfloat16 ob[4] = { F2B(dx * rstd * gg.x + bb.x), F2B(dy * rstd * gg.y + bb.y),
                                     F2B(dz * rstd * gg.z + bb.z), F2B(dw * rstd * gg.w + bb.w) };
            *(ushort4*)(xw + (size_t)(rb + k) * CDIM + c0) = *(const ushort4*)ob;
        }
    }
}

// ---------------- LayerNorms (4 rows per wave, batched loads) ----------------

__global__ __launch_bounds__(256) void ln_a_kernel(
    const __hip_bfloat16* __restrict__ s,   // xw + attn (pre-summed by MODE_ATTN epilogue)
    const float* __restrict__ g, const float* __restrict__ b,
    __hip_bfloat16* a2) {
    const int lane = threadIdx.x & 63;
    const int rb = blockIdx.x * 16 + (threadIdx.x >> 6) * 4;
    const int c0 = lane * 4;
    ushort4 sv[4];
#pragma unroll
    for (int k = 0; k < 4; ++k)
        sv[k] = *(const ushort4*)(s + (size_t)(rb + k) * CDIM + c0);
    float4 gg = *(const float4*)(g + c0);
    float4 bb = *(const float4*)(b + c0);
#pragma unroll
    for (int k = 0; k < 4; ++k) {
        float tx = bf2f(sv[k].x), ty = bf2f(sv[k].y), tz = bf2f(sv[k].z), tw = bf2f(sv[k].w);
        float mean = wave_sum64(tx + ty + tz + tw) * (1.f / 256.f);
        float dx = tx - mean, dy = ty - mean, dz = tz - mean, dw = tw - mean;
        float var = wave_sum64(dx * dx + dy * dy + dz * dz + dw * dw) * (1.f / 256.f);
        float rstd = rsqrtf(var + 1e-5f);
        __hip_bfloat16 ob[4] = { F2B(dx * rstd * gg.x + bb.x), F2B(dy * rstd * gg.y + bb.y),
                                 F2B(dz * rstd * gg.z + bb.z), F2B(dw * rstd * gg.w + bb.w) };
        *(ushort4*)((__hip_bfloat16*)a2 + (size_t)(rb + k) * CDIM + c0) = *(const ushort4*)ob;
    }
}

__global__ __launch_bounds__(256) void ln2_kernel(
    const float* __restrict__ xres,
    const float* __restrict__ g, const float* __restrict__ b,
    __hip_bfloat16* __restrict__ hin) {
    const int lane = threadIdx.x & 63;
    const int rb = blockIdx.x * 16 + (threadIdx.x >> 6) * 4;
    const int c0 = lane * 4;
    float4 v[4];
#pragma unroll
    for (int k = 0; k < 4; ++k)
        v[k] = *(const float4*)(xres + (size_t)(rb + k) * CDIM + c0);
    float4 gg = *(const float4*)(g + c0);
    float4 bb = *(const float4*)(b + c0);
#pragma unroll
    for (int k = 0; k < 4; ++k) {
        float mean = wave_sum64(v[k].x + v[k].y + v[k].z + v[k].w) * (1.f / 256.f);
        float dx = v[k].x - mean, dy = v[k].y - mean, dz = v[k].z - mean, dw = v[k].w - mean;
        float var = wave_sum64(dx * dx + dy * dy + dz * dz + dw * dw) * (1.f / 256.f);
        float rstd = rsqrtf(var + 1e-5f);
        __hip_bfloat16 ob[4] = { F2B(dx * rstd * gg.x + bb.x), F2B(dy * rstd * gg.y + bb.y),
                                 F2B(dz * rstd * gg.z + bb.z), F2B(dw * rstd * gg.w + bb.w) };
        *(ushort4*)(hin + (size_t)(rb + k) * CDIM + c0) = *(const ushort4*)ob;
    }
}

// ---------------- fused sampling v3: full async LDS staging (value + offaw) ----------------

__global__ __launch_bounds__(512, 4) void sample_fused(
    const __half* __restrict__ offaw,          // M x 128 (96 off | 32 aw), f16
    const __hip_bfloat16* __restrict__ value,  // M x 256
    __hip_bfloat16* __restrict__ ai) {         // M x 256
    __shared__ __align__(16) __hip_bfloat16 vs[98 * 256];   // 50176 B
    __shared__ __align__(16) __half os[98 * 128];           // 25088 B
    const int tid = threadIdx.x;
    const int w = blockIdx.x;

#if HAS_GLL
    {
        const uint4* vsrc = (const uint4*)(value + (size_t)w * 98 * CDIM);
#pragma unroll
        for (int k = 0; k < 7; ++k) {
            int i = tid + k * 512;
            if (i < 3136)
                __builtin_amdgcn_global_load_lds(
                    (const __attribute__((address_space(1))) void*)(vsrc + i),
                    (__attribute__((address_space(3))) void*)(((uint4*)vs) + i), 16, 0, 0);
        }
        const uint4* osrc = (const uint4*)(offaw + (size_t)w * 98 * 128);
#pragma unroll
        for (int k = 0; k < 4; ++k) {
            int i = tid + k * 512;
            if (i < 1568)
                __builtin_amdgcn_global_load_lds(
                    (const __attribute__((address_space(1))) void*)(osrc + i),
                    (__attribute__((address_space(3))) void*)(((uint4*)os) + i), 16, 0, 0);
        }
    }
#else
    {
        const uint4* vsrc = (const uint4*)(value + (size_t)w * 98 * CDIM);
        uint4* vdst = (uint4*)vs;
        for (int i = tid; i < 3136; i += 512) vdst[i] = vsrc[i];
        const uint4* osrc = (const uint4*)(offaw + (size_t)w * 98 * 128);
        uint4* odst = (uint4*)os;
        for (int i = tid; i < 1568; i += 512) odst[i] = osrc[i];
    }
#endif
    __syncthreads();

    const int lane  = tid & 63;
    const int wave  = tid >> 6;
    const int h     = lane >> 3;
    const int s     = lane & 7;
    const int p     = s >> 1;
    const int jbase = (s & 1) * 4;
    const int boff  = lane * 8;
    const int gbase = lane & ~7;

    for (int r = wave; r < 98; r += 8) {
        int z = r / 49, n2 = r - z * 49, yy = n2 / 7, xx = n2 - yy * 7;
        const __half* orow = os + r * 128;

        float l0 = __half2float(orow[96 + h * 4 + 0]);
        float l1 = __half2float(orow[96 + h * 4 + 1]);
        float l2 = __half2float(orow[96 + h * 4 + 2]);
        float l3 = __half2float(orow[96 + h * 4 + 3]);
        float mx = fmaxf(fmaxf(l0, l1), fmaxf(l2, l3));
        float e0 = __expf(l0 - mx), e1 = __expf(l1 - mx), e2 = __expf(l2 - mx), e3 = __expf(l3 - mx);
        float inv = 1.f / (e0 + e1 + e2 + e3);
        float ep = (p == 0) ? e0 : (p == 1) ? e1 : (p == 2) ? e2 : e3;
        float wp = ep * inv;

        float ox = __half2float(orow[h * 12 + p * 3 + 0]);
        float oy = __half2float(orow[h * 12 + p * 3 + 1]);
        float oz = __half2float(orow[h * 12 + p * 3 + 2]);
        float px = (float)xx + ox, py = (float)yy + oy, pz = (float)z + oz;
        float fx0 = floorf(px), fy0 = floorf(py), fz0 = floorf(pz);
        int ix = (int)fx0, iy = (int)fy0, iz = (int)fz0;
        float fx = px - fx0, fy = py - fy0, fz = pz - fz0;

        uint packed[4];
#pragma unroll
        for (int jj = 0; jj < 4; ++jj) {
            int j = jbase + jj;
            int dzz = j >> 2, dyy = (j >> 1) & 1, dxx = j & 1;
            int zi = iz + dzz, yi = iy + dyy, xi = ix + dxx;
            float wz = dzz ? fz : 1.f - fz;
            float wy = dyy ? fy : 1.f - fy;
            float wxw = dxx ? fx : 1.f - fx;
            bool valid = (zi >= 0) & (zi < 2) & (yi >= 0) & (yi < 7) & (xi >= 0) & (xi < 7);
            float wc = valid ? wp * wz * wy * wxw : 0.f;
            int zc = min(max(zi, 0), 1), yc = min(max(yi, 0), 6), xc = min(max(xi, 0), 6);
            int idx = zc * 49 + yc * 7 + xc;
            packed[jj] = ((uint)(idx * 512) << 16) | (uint)__half_as_ushort(__float2half(wc));
        }

        float a0 = 0.f, a1 = 0.f, a2 = 0.f, a3 = 0.f;
#pragma unroll
        for (int jj = 0; jj < 4; ++jj) {
            uint mine = packed[jj];
#pragma unroll
            for (int sl = 0; sl < 8; ++sl) {
                uint pk = __shfl(mine, gbase + sl, 64);
                float wj = __half2float(__ushort_as_half((unsigned short)(pk & 0xffffu)));
                ushort4 v = *(const ushort4*)((const char*)vs + (pk >> 16) + boff);
                a0 += wj * bf2f(v.x);
                a1 += wj * bf2f(v.y);
                a2 += wj * bf2f(v.z);
                a3 += wj * bf2f(v.w);
            }
        }
        __hip_bfloat16 ob[4] = { F2B(a0), F2B(a1), F2B(a2), F2B(a3) };
        *(ushort4*)(ai + ((size_t)w * 98 + r) * CDIM + lane * 4) = *(const ushort4*)ob;
    }
}

// ---------------- MFMA GEMM (double-buffered async staging) ----------------

template <int MODE>
__global__ __launch_bounds__(256) void gemm_bt(
    const __hip_bfloat16* __restrict__ A,
    const __hip_bfloat16* __restrict__ Bt,
    const int N, const int K,
    const float* __restrict__ bias0,
    const float* __restrict__ bias1,
    const float* __restrict__ bias2,
    void* C,
    void* extra,
    const void* extra2,
    const float* __restrict__ csum) {
    __shared__ __align__(16) __hip_bfloat16 As[2][128 * 32];
    __shared__ __align__(16) __hip_bfloat16 Bs[2][128 * 32];
    const int tid  = threadIdx.x;
    const int lane = tid & 63;
    const int wave = tid >> 6;
    const int wm = (wave >> 1) * 64;
    const int wn = (wave & 1) * 64;
    const int row0 = blockIdx.x * 128;
    const int col0 = blockIdx.y * 128;
    const int l15 = lane & 15;
    const int quad = lane >> 4;

    floatx4 acc[4][4] = {};

    const int sr = tid >> 2;
    const int sk = (tid & 3) * 8;

    const __hip_bfloat16* Ab = A + (size_t)row0 * K + sr * (size_t)K + sk;
    const __hip_bfloat16* Bb = Bt + (size_t)col0 * K + sr * (size_t)K + sk;
    const size_t half64 = (size_t)64 * K;

    auto stage = [&](int buf, int k0) {
#if HAS_GLL
        __builtin_amdgcn_global_load_lds(
            (const __attribute__((address_space(1))) void*)(Ab + k0),
            (__attribute__((address_space(3))) void*)(&As[buf][sr * 32 + sk]), 16, 0, 0);
        __builtin_amdgcn_global_load_lds(
            (const __attribute__((address_space(1))) void*)(Ab + half64 + k0),
            (__attribute__((address_space(3))) void*)(&As[buf][(sr + 64) * 32 + sk]), 16, 0, 0);
        __builtin_amdgcn_global_load_lds(
            (const __attribute__((address_space(1))) void*)(Bb + k0),
            (__attribute__((address_space(3))) void*)(&Bs[buf][sr * 32 + sk]), 16, 0, 0);
        __builtin_amdgcn_global_load_lds(
            (const __attribute__((address_space(1))) void*)(Bb + half64 + k0),
            (__attribute__((address_space(3))) void*)(&Bs[buf][(sr + 64) * 32 + sk]), 16, 0, 0);
#else
        *reinterpret_cast<uint4*>(&As[buf][sr * 32 + sk]) = *reinterpret_cast<const uint4*>(Ab + k0);
        *reinterpret_cast<uint4*>(&As[buf][(sr + 64) * 32 + sk]) = *reinterpret_cast<const uint4*>(Ab + half64 + k0);
        *reinterpret_cast<uint4*>(&Bs[buf][sr * 32 + sk]) = *reinterpret_cast<const uint4*>(Bb + k0);
        *reinterpret_cast<uint4*>(&Bs[buf][(sr + 64) * 32 + sk]) = *reinterpret_cast<const uint4*>(Bb + half64 + k0);
#endif
    };

    const int nk = K >> 5;
    stage(0, 0);
    for (int t = 0; t < nk; ++t) {
        __syncthreads();
        if (t + 1 < nk) stage((t + 1) & 1, (t + 1) * 32);
        const __hip_bfloat16* Asb = As[t & 1];
        const __hip_bfloat16* Bsb = Bs[t & 1];
        bf16x8 af[4], bfg[4];
#pragma unroll
        for (int i = 0; i < 4; ++i)
            af[i] = *reinterpret_cast<const bf16x8*>(&Asb[(wm + i * 16 + l15) * 32 + quad * 8]);
#pragma unroll
        for (int j = 0; j < 4; ++j)
            bfg[j] = *reinterpret_cast<const bf16x8*>(&Bsb[(wn + j * 16 + l15) * 32 + quad * 8]);
#pragma unroll
        for (int i = 0; i < 4; ++i)
#pragma unroll
            for (int j = 0; j < 4; ++j)
                acc[i][j] = __builtin_amdgcn_mfma_f32_16x16x32_bf16(af[i], bfg[j], acc[i][j], 0, 0, 0);
    }

#pragma unroll
    for (int i = 0; i < 4; ++i) {
#pragma unroll
        for (int j = 0; j < 4; ++j) {
#pragma unroll
            for (int rr = 0; rr < 4; ++rr) {
                int row = row0 + wm + i * 16 + quad * 4 + rr;
                int col = col0 + wn + j * 16 + l15;
                float v = acc[i][j][rr];
                if constexpr (MODE == MODE_BF16) {
                    v += bias0[col];
                    ((__hip_bfloat16*)C)[(size_t)row * N + col] = F2B(v);
                } else if constexpr (MODE == MODE_ATTN) {
                    v += bias0[col];
                    const __hip_bfloat16* xwp = (const __hip_bfloat16*)extra2;
                    v += B2F(xwp[(size_t)row * 256 + col]);
                    ((__hip_bfloat16*)C)[(size_t)row * N + col] = F2B(v);
                } else if constexpr (MODE == MODE_VALOFFAW) {
                    if (col < 256) {
                        v += bias0[col];
                        ((__hip_bfloat16*)C)[(size_t)row * 256 + col] = F2B(v);
                    } else {
                        int c2 = col - 256;
                        const float* diag = (const float*)extra2;
                        v += (c2 < 96 ? bias1[c2] : bias2[c2 - 96]);
                        v += diag[row] * csum[c2];
                        ((__half*)extra)[(size_t)row * 128 + c2] = __float2half(v);
                    }
                } else if constexpr (MODE == MODE_REVERSE) {
                    v += bias0[col];
                    int tok; win_decode(row, tok);
                    const float* xin = (const float*)extra2;
                    ((float*)C)[(size_t)tok * CDIM + col] = xin[(size_t)tok * CDIM + col] + v;
                }
            }
        }
    }
}

// ---------------- fused MLP v4: round-6 structure + correct bank-slot swizzle ----------------
// Identical structure to the 150-us round-6 kernel (128 rows, global_load_lds
// staging, 2 barriers/chunk, transient b2 loads). Only change: LDS tiles are
// slot-swizzled byte ^= ((row>>1)&3)<<4 (row bits 1-2 into byte bits 4-5), so
// every consecutive-8-lane group of a ds_read_b128 hits all 8 16B bank-slots
// (round-7's (row&7)<<4 permuted within the same slot subset -> no effect).
// Staging keeps global_load_lds with inverse-swizzled GLOBAL source (rule #21):
// thread (row, kq') loads global column (kq' ^ ((row>>1)&3)).

__global__ __launch_bounds__(512, 4) void mlp_fused(
    const __hip_bfloat16* __restrict__ hin,   // M x 256
    const __hip_bfloat16* __restrict__ fc1T,  // 1024 x 256 (N,K)
    const __hip_bfloat16* __restrict__ fc2T,  // 256 x 1024 (N,K)
    const float* __restrict__ fc1_b, const float* __restrict__ fc2_b,
    float* __restrict__ out) {                // M x 256 f32, in-place xres+=mlp
    __shared__ __align__(16) __hip_bfloat16 hs[8 * 128 * 32];  // 64 KB: hin as 8 swizzled ktiles
    __shared__ __align__(16) __hip_bfloat16 as[2 * 128 * 32];  // 16 KB: act as 2 swizzled ktiles
    const int tid  = threadIdx.x;
    const int lane = tid & 63;
    const int w    = tid >> 6;
    const int r0   = blockIdx.x * 128;
    const int l15  = lane & 15;
    const int quad = lane >> 4;
    const int wm   = (w >> 2) * 64;   // row group (0/64)
    const int wn   = (w & 3) * 64;    // out col group
    const int ac   = (w & 3) * 16;    // act col group within 64

    // stage hin: LDS dest lane-linear (tid*16 B per ktile), global source
    // column permuted by the inverse swizzle: kq = (tid&3) ^ ((row>>1)&3).
    {
        const int row = tid >> 2;
        const int kq  = (tid & 3) ^ ((row >> 1) & 3);
#if HAS_GLL
#pragma unroll
        for (int kt = 0; kt < 8; ++kt)
            __builtin_amdgcn_global_load_lds(
                (const __attribute__((address_space(1))) void*)(hin + (size_t)(r0 + row) * 256 + kt * 32 + kq * 8),
                (__attribute__((address_space(3))) void*)(&hs[kt * 4096 + row * 32 + (tid & 3) * 8]), 16, 0, 0);
#else
#pragma unroll
        for (int kt = 0; kt < 8; ++kt)
            *(uint4*)(&hs[kt * 4096 + row * 32 + (tid & 3) * 8]) =
                *(const uint4*)(hin + (size_t)(r0 + row) * 256 + kt * 32 + kq * 8);
#endif
    }
    floatx4 acc[4][4] = {};
    const int kt2 = (ac + l15) >> 5, ko = (ac + l15) & 31;   // act logical write coords
    // swizzled A-fragment byte offsets within a ktile (constant across kk)
    uint aoff[4];
#pragma unroll
    for (int i = 0; i < 4; ++i) {
        int row = wm + i * 16 + l15;
        aoff[i] = (uint)((row * 64 + quad * 16) ^ (((row >> 1) & 3) << 4));
    }
    __syncthreads();

    for (int kk = 0; kk < 1024; kk += 64) {
        // ---- phase 1: act = gelu(hs @ fc1T[:, kk..kk+64) + b1), this wave's 16 cols ----
        floatx4 pa[4] = {};
#pragma unroll
        for (int ks = 0; ks < 8; ++ks) {
            bf16x8 b1 = *(const bf16x8*)(fc1T + (size_t)(kk + ac + l15) * 256 + ks * 32 + quad * 8);
#pragma unroll
            for (int i = 0; i < 4; ++i) {
                bf16x8 a = *(const bf16x8*)((const char*)hs + ks * 8192 + aoff[i]);
                pa[i] = __builtin_amdgcn_mfma_f32_16x16x32_bf16(a, b1, pa[i], 0, 0, 0);
            }
        }
        float bb = fc1_b[kk + ac + l15];
        __syncthreads();   // prev phase-2 reads of `as` complete
#pragma unroll
        for (int i = 0; i < 4; ++i) {
#pragma unroll
            for (int rr = 0; rr < 4; ++rr) {
                float v = pa[i][rr] + bb;
                float t2 = 1.5957691216057308f * (v + 0.044715f * v * v * v);
                v = v / (1.f + __expf(-t2));
                int row = wm + i * 16 + quad * 4 + rr;
                uint wb = (uint)((row * 64 + ko * 2) ^ (((row >> 1) & 3) << 4));
                *(__hip_bfloat16*)((char*)as + kt2 * 8192 + wb) = F2B(v);
            }
        }
        __syncthreads();   // `as` ready
        // ---- phase 2: acc += act @ fc2T[:, kk..kk+64)^T (transient B loads) ----
#pragma unroll
        for (int ks = 0; ks < 2; ++ks) {
            bf16x8 a4[4];
#pragma unroll
            for (int i = 0; i < 4; ++i)
                a4[i] = *(const bf16x8*)((const char*)as + ks * 8192 + aoff[i]);
#pragma unroll
            for (int j = 0; j < 4; ++j) {
                bf16x8 b2 = *(const bf16x8*)(fc2T + (size_t)(wn + j * 16 + l15) * 1024 + kk + ks * 32 + quad * 8);
#pragma unroll
                for (int i = 0; i < 4; ++i)
                    acc[i][j] = __builtin_amdgcn_mfma_f32_16x16x32_bf16(a4[i], b2, acc[i][j], 0, 0, 0);
            }
        }
    }
    // epilogue: out += acc + fc2_b (f32 in-place residual)
#pragma unroll
    for (int i = 0; i < 4; ++i)
#pragma unroll
        for (int j = 0; j < 4; ++j)
#pragma unroll
            for (int rr = 0; rr < 4; ++rr) {
                int row = r0 + wm + i * 16 + quad * 4 + rr;
                int col = wn + j * 16 + l15;
                out[(size_t)row * 256 + col] += acc[i][j][rr] + fc2_b[col];
            }
}

// ---------------- host launcher ----------------

extern "C" void kernel_launch(void* const* d_in, const int* in_sizes, int n_in,
                              void* d_out, int out_size, void* d_ws, size_t ws_size,
                              hipStream_t stream) {
    const float* x      = (const float*)d_in[0];
    const float* mask   = (const float*)d_in[1];
    const float* n1g    = (const float*)d_in[2];
    const float* n1b    = (const float*)d_in[3];
    const float* val_w  = (const float*)d_in[4];
    const float* val_b  = (const float*)d_in[5];
    const float* off_w  = (const float*)d_in[6];
    const float* off_b  = (const float*)d_in[7];
    const float* aw_w   = (const float*)d_in[8];
    const float* aw_b   = (const float*)d_in[9];
    const float* out_w  = (const float*)d_in[10];
    const float* out_b  = (const float*)d_in[11];
    const float* ang    = (const float*)d_in[12];
    const float* anb    = (const float*)d_in[13];
    const float* proj_w = (const float*)d_in[14];
    const float* proj_b = (const float*)d_in[15];
    const float* n2g    = (const float*)d_in[16];
    const float* n2b    = (const float*)d_in[17];
    const float* fc1_w  = (const float*)d_in[18];
    const float* fc1_b  = (const float*)d_in[19];
    const float* fc2_w  = (const float*)d_in[20];
    const float* fc2_b  = (const float*)d_in[21];

    char* ws = (char*)d_ws;
    size_t o = 0;
    auto alloc = [&](size_t bytes) {
        size_t r = o;
        o += (bytes + 255) & ~(size_t)255;
        return r;
    };
    const size_t M = MROWS;
    const size_t REGION_B = M * 128 * 2 + M * 256 * 2;                 // offaw + ai

    __hip_bfloat16* valT    = (__hip_bfloat16*)(ws + alloc(256 * 256 * 2));
    __hip_bfloat16* offawT  = (__hip_bfloat16*)(ws + alloc(128 * 256 * 2));
    __hip_bfloat16* outT    = (__hip_bfloat16*)(ws + alloc(256 * 256 * 2));
    __hip_bfloat16* projT   = (__hip_bfloat16*)(ws + alloc(256 * 256 * 2));
    __hip_bfloat16* fc1T    = (__hip_bfloat16*)(ws + alloc(1024 * 256 * 2));
    __hip_bfloat16* fc2T    = (__hip_bfloat16*)(ws + alloc(256 * 1024 * 2));
    float*          csum    = (float*)(ws + alloc(128 * 4));
    float*          diag    = (float*)(ws + alloc(M * 4));
    char*           slab1   = ws + alloc(M * 256 * 2);                 // xw -> a2 -> hin
    char*           region  = ws + alloc(REGION_B);                    // multi-use
    (void)ws_size; (void)in_sizes; (void)n_in; (void)out_size;

    __hip_bfloat16* xw    = (__hip_bfloat16*)slab1;
    __hip_bfloat16* a2    = (__hip_bfloat16*)slab1;
    __hip_bfloat16* hin   = (__hip_bfloat16*)slab1;
    __half*         offaw = (__half*)region;                           // M x 128 f16
    __hip_bfloat16* ai    = (__hip_bfloat16*)(region + M * 128 * 2);   // M x 256 bf16
    __hip_bfloat16* value = (__hip_bfloat16*)d_out;                    // bf16 scratch
    __hip_bfloat16* attn  = (__hip_bfloat16*)d_out;                    // bf16 scratch (xw+attn)
    float*          xres  = (float*)d_out;                             // f32 trunk

    dim3 blk(256);
    // 0. fused front: transposes + diag + csum + LN1 (16 rows/block)
    hipLaunchKernelGGL(fused_pre, dim3(2944 + 196 + 1 + MROWS / 16), blk, 0, stream,
                       x, n1g, n1b, xw, mask, diag, csum,
                       val_w, off_w, aw_w, out_w, proj_w, fc1_w, fc2_w,
                       valT, offawT, outT, projT, fc1T, fc2T);
    // 2+3 merged. N=384 over [valT|offawT]: value -> d_out bf16, offaw -> region f16
    hipLaunchKernelGGL((gemm_bt<MODE_VALOFFAW>), dim3(MROWS / 128, 3), blk, 0, stream,
                       xw, valT, 384, 256, val_b, off_b, aw_b,
                       (void*)value, (void*)offaw, (const void*)diag, csum);
    // 4. ai = fully-LDS-staged prep + gather sample(value)
    hipLaunchKernelGGL(sample_fused, dim3(MROWS / 98), dim3(512), 0, stream,
                       offaw, value, ai);
    // 5. attn = xw + (ai @ out_w + out_b)    (d_out bf16 scratch; value dead)
    hipLaunchKernelGGL((gemm_bt<MODE_ATTN>), dim3(MROWS / 128, 2), blk, 0, stream,
                       ai, outT, 256, 256, out_b, (const float*)nullptr, (const float*)nullptr,
                       (void*)attn, (void*)nullptr, (const void*)xw, (const float*)nullptr);
    // 6. a2 = LN(attn)   (16 rows/block)
    hipLaunchKernelGGL(ln_a_kernel, dim3(MROWS / 16), blk, 0, stream, attn, ang, anb, a2);
    // 7. xres = x + reverse(a2 @ proj + b)   (d_out f32, token order)
    hipLaunchKernelGGL((gemm_bt<MODE_REVERSE>), dim3(MROWS / 128, 2), blk, 0, stream,
                       a2, projT, 256, 256, proj_b, (const float*)nullptr, (const float*)nullptr,
                       (void*)xres, (void*)nullptr, (const void*)x, (const float*)nullptr);
    // 8. hin = LN2(xres)  (16 rows/block)
    hipLaunchKernelGGL(ln2_kernel, dim3(MROWS / 16), blk, 0, stream, xres, n2g, n2b, hin);
    // 9. fused MLP: out = xres + gelu(hin@fc1+b1)@fc2 + b2, in-place on d_out
    hipLaunchKernelGGL(mlp_fused, dim3(MROWS / 128), dim3(512), 0, stream,
                       hin, fc1T, fc2T, fc1_b, fc2_b, (float*)d_out);
}

// Round 11
// 451.576 us; speedup vs baseline: 1.0901x; 1.0901x over previous
//
#include <hip/hip_runtime.h>
#include <hip/hip_bf16.h>
#include <hip/hip_fp16.h>

#define B2F(x) __bfloat162float(x)
#define F2B(x) __float2bfloat16(x)

typedef __bf16 bf16x8 __attribute__((ext_vector_type(8)));
typedef float floatx4 __attribute__((ext_vector_type(4)));

static constexpr int MROWS = 50176;   // 512 windows * 98 tokens
static constexpr int CDIM  = 256;

enum { MODE_BF16 = 0, MODE_VALOFFAW = 1 };

#if defined(__has_builtin)
#if __has_builtin(__builtin_amdgcn_global_load_lds)
#define HAS_GLL 1
#endif
#endif
#ifndef HAS_GLL
#define HAS_GLL 0
#endif

// ---------------- helpers ----------------

__device__ __forceinline__ void win_decode(int r, int& tok) {
    int w = r / 98, n = r - w * 98;
    int dB = w >> 6, hB = (w >> 3) & 7, wB = w & 7;
    int z = n / 49, n2 = n - z * 49, yy = n2 / 7, xx = n2 - yy * 7;
    tok = ((dB * 2 + z) * 56 + hB * 7 + yy) * 56 + wB * 7 + xx;
}

__device__ __forceinline__ float bf2f(unsigned short u) {
    return __uint_as_float(((unsigned)u) << 16);
}

__device__ __forceinline__ float wave_sum64(float v) {
#pragma unroll
    for (int off = 32; off > 0; off >>= 1) v += __shfl_xor(v, off, 64);
    return v;
}

// ---------------- fused front: weight transpose + diag/csum + LN1 (one launch) ----------------

__global__ __launch_bounds__(256) void fused_pre(
    const float* __restrict__ x, const float* __restrict__ n1g, const float* __restrict__ n1b,
    __hip_bfloat16* __restrict__ xw,
    const float* __restrict__ mask, float* __restrict__ diag, float* __restrict__ csum,
    const float* __restrict__ val_w, const float* __restrict__ off_w,
    const float* __restrict__ aw_w,  const float* __restrict__ out_w,
    const float* __restrict__ proj_w, const float* __restrict__ fc1_w,
    const float* __restrict__ fc2_w,
    __hip_bfloat16* __restrict__ valT, __hip_bfloat16* __restrict__ offawT,
    __hip_bfloat16* __restrict__ outT, __hip_bfloat16* __restrict__ projT,
    __hip_bfloat16* __restrict__ fc1T, __hip_bfloat16* __restrict__ fc2T) {
    const int bid = blockIdx.x;
    const int tid = threadIdx.x;

    if (bid < 2944) {   // ---- transpose ----
        const float* src; __hip_bfloat16* dst; int K, N, base;
        if (bid < 256)       { src = val_w;  dst = valT;            K = 256;  N = 256;  base = 0; }
        else if (bid < 352)  { src = off_w;  dst = offawT;          K = 256;  N = 96;   base = 256; }
        else if (bid < 384)  { src = aw_w;   dst = offawT + 96*256; K = 256;  N = 32;   base = 352; }
        else if (bid < 640)  { src = out_w;  dst = outT;            K = 256;  N = 256;  base = 384; }
        else if (bid < 896)  { src = proj_w; dst = projT;           K = 256;  N = 256;  base = 640; }
        else if (bid < 1920) { src = fc1_w;  dst = fc1T;            K = 256;  N = 1024; base = 896; }
        else                 { src = fc2_w;  dst = fc2T;            K = 1024; N = 256;  base = 1920; }
        int i = (bid - base) * 256 + tid;
        if (i >= K * N) return;
        int nn = i / K, kk = i - nn * K;
        dst[(size_t)nn * K + kk] = F2B(src[(size_t)kk * N + nn]);
    } else if (bid < 3140) {   // ---- diag ----
        int r = (bid - 2944) * 256 + tid;
        int n = r % 98;
        int z = n / 49, n2 = n - z * 49, yy = n2 / 7, xx = n2 - yy * 7;
        const float* mb = mask + (size_t)r * 98;
        float m = mb[z * 49 + yy * 7 + xx];
        float sz = 0.f, sy = 0.f, sx = 0.f;
        for (int k = 0; k <= z; ++k)  sz += mb[k * 49 + yy * 7 + xx];
        for (int k = 0; k <= yy; ++k) sy += mb[z * 49 + k * 7 + xx];
        for (int k = 0; k <= xx; ++k) sx += mb[z * 49 + yy * 7 + k];
        const float PI = 3.14159265358979323846f;
        diag[r] = m * (sinf(sx * m / PI) + sinf(sy * m) + sz * m / PI);
    } else if (bid == 3140) {  // ---- csum (column sums of f32 weights) ----
        if (tid < 96) {
            float s = 0.f;
            for (int k = 0; k < 256; ++k) s += off_w[(size_t)k * 96 + tid];
            csum[tid] = s;
        } else if (tid < 128) {
            int n = tid - 96;
            float s = 0.f;
            for (int k = 0; k < 256; ++k) s += aw_w[(size_t)k * 32 + n];
            csum[tid] = s;
        }
    } else {                   // ---- LN1, 4 rows per wave ----
        const int lane = tid & 63;
        const int rb = (bid - 3141) * 16 + (tid >> 6) * 4;
        const int c0 = lane * 4;
        float4 v[4];
#pragma unroll
        for (int k = 0; k < 4; ++k) {
            int tok; win_decode(rb + k, tok);
            v[k] = *(const float4*)(x + (size_t)tok * CDIM + c0);
        }
        float4 gg = *(const float4*)(n1g + c0);
        float4 bb = *(const float4*)(n1b + c0);
#pragma unroll
        for (int k = 0; k < 4; ++k) {
            float mean = wave_sum64(v[k].x + v[k].y + v[k].z + v[k].w) * (1.f / 256.f);
            float dx = v[k].x - mean, dy = v[k].y - mean, dz = v[k].z - mean, dw = v[k].w - mean;
            float var = wave_sum64(dx * dx + dy * dy + dz * dz + dw * dw) * (1.f / 256.f);
            float rstd = rsqrtf(var + 1e-5f);
            __hip_bfloat16 ob[4] = { F2B(dx * rstd * gg.x + bb.x), F2B(dy * rstd * gg.y + bb.y),
                                     F2B(dz * rstd * gg.z + bb.z), F2B(dw * rstd * gg.w + bb.w) };
            *(ushort4*)(xw + (size_t)(rb + k) * CDIM + c0) = *(const ushort4*)ob;
        }
    }
}

// ---------------- fused sampling v3: full async LDS staging (value + offaw) ----------------

__global__ __launch_bounds__(512, 4) void sample_fused(
    const __half* __restrict__ offaw,          // M x 128 (96 off | 32 aw), f16
    const __hip_bfloat16* __restrict__ value,  // M x 256
    __hip_bfloat16* __restrict__ ai) {         // M x 256
    __shared__ __align__(16) __hip_bfloat16 vs[98 * 256];   // 50176 B
    __shared__ __align__(16) __half os[98 * 128];           // 25088 B
    const int tid = threadIdx.x;
    const int w = blockIdx.x;

#if HAS_GLL
    {
        const uint4* vsrc = (const uint4*)(value + (size_t)w * 98 * CDIM);
#pragma unroll
        for (int k = 0; k < 7; ++k) {
            int i = tid + k * 512;
            if (i < 3136)
                __builtin_amdgcn_global_load_lds(
                    (const __attribute__((address_space(1))) void*)(vsrc + i),
                    (__attribute__((address_space(3))) void*)(((uint4*)vs) + i), 16, 0, 0);
        }
        const uint4* osrc = (const uint4*)(offaw + (size_t)w * 98 * 128);
#pragma unroll
        for (int k = 0; k < 4; ++k) {
            int i = tid + k * 512;
            if (i < 1568)
                __builtin_amdgcn_global_load_lds(
                    (const __attribute__((address_space(1))) void*)(osrc + i),
                    (__attribute__((address_space(3))) void*)(((uint4*)os) + i), 16, 0, 0);
        }
    }
#else
    {
        const uint4* vsrc = (const uint4*)(value + (size_t)w * 98 * CDIM);
        uint4* vdst = (uint4*)vs;
        for (int i = tid; i < 3136; i += 512) vdst[i] = vsrc[i];
        const uint4* osrc = (const uint4*)(offaw + (size_t)w * 98 * 128);
        uint4* odst = (uint4*)os;
        for (int i = tid; i < 1568; i += 512) odst[i] = osrc[i];
    }
#endif
    __syncthreads();

    const int lane  = tid & 63;
    const int wave  = tid >> 6;
    const int h     = lane >> 3;
    const int s     = lane & 7;
    const int p     = s >> 1;
    const int jbase = (s & 1) * 4;
    const int boff  = lane * 8;
    const int gbase = lane & ~7;

    for (int r = wave; r < 98; r += 8) {
        int z = r / 49, n2 = r - z * 49, yy = n2 / 7, xx = n2 - yy * 7;
        const __half* orow = os + r * 128;

        float l0 = __half2float(orow[96 + h * 4 + 0]);
        float l1 = __half2float(orow[96 + h * 4 + 1]);
        float l2 = __half2float(orow[96 + h * 4 + 2]);
        float l3 = __half2float(orow[96 + h * 4 + 3]);
        float mx = fmaxf(fmaxf(l0, l1), fmaxf(l2, l3));
        float e0 = __expf(l0 - mx), e1 = __expf(l1 - mx), e2 = __expf(l2 - mx), e3 = __expf(l3 - mx);
        float inv = 1.f / (e0 + e1 + e2 + e3);
        float ep = (p == 0) ? e0 : (p == 1) ? e1 : (p == 2) ? e2 : e3;
        float wp = ep * inv;

        float ox = __half2float(orow[h * 12 + p * 3 + 0]);
        float oy = __half2float(orow[h * 12 + p * 3 + 1]);
        float oz = __half2float(orow[h * 12 + p * 3 + 2]);
        float px = (float)xx + ox, py = (float)yy + oy, pz = (float)z + oz;
        float fx0 = floorf(px), fy0 = floorf(py), fz0 = floorf(pz);
        int ix = (int)fx0, iy = (int)fy0, iz = (int)fz0;
        float fx = px - fx0, fy = py - fy0, fz = pz - fz0;

        uint packed[4];
#pragma unroll
        for (int jj = 0; jj < 4; ++jj) {
            int j = jbase + jj;
            int dzz = j >> 2, dyy = (j >> 1) & 1, dxx = j & 1;
            int zi = iz + dzz, yi = iy + dyy, xi = ix + dxx;
            float wz = dzz ? fz : 1.f - fz;
            float wy = dyy ? fy : 1.f - fy;
            float wxw = dxx ? fx : 1.f - fx;
            bool valid = (zi >= 0) & (zi < 2) & (yi >= 0) & (yi < 7) & (xi >= 0) & (xi < 7);
            float wc = valid ? wp * wz * wy * wxw : 0.f;
            int zc = min(max(zi, 0), 1), yc = min(max(yi, 0), 6), xc = min(max(xi, 0), 6);
            int idx = zc * 49 + yc * 7 + xc;
            packed[jj] = ((uint)(idx * 512) << 16) | (uint)__half_as_ushort(__float2half(wc));
        }

        float a0 = 0.f, a1 = 0.f, a2 = 0.f, a3 = 0.f;
#pragma unroll
        for (int jj = 0; jj < 4; ++jj) {
            uint mine = packed[jj];
#pragma unroll
            for (int sl = 0; sl < 8; ++sl) {
                uint pk = __shfl(mine, gbase + sl, 64);
                float wj = __half2float(__ushort_as_half((unsigned short)(pk & 0xffffu)));
                ushort4 v = *(const ushort4*)((const char*)vs + (pk >> 16) + boff);
                a0 += wj * bf2f(v.x);
                a1 += wj * bf2f(v.y);
                a2 += wj * bf2f(v.z);
                a3 += wj * bf2f(v.w);
            }
        }
        __hip_bfloat16 ob[4] = { F2B(a0), F2B(a1), F2B(a2), F2B(a3) };
        *(ushort4*)(ai + ((size_t)w * 98 + r) * CDIM + lane * 4) = *(const ushort4*)ob;
    }
}

// ---------------- MFMA GEMM (double-buffered async staging) ----------------
// Used for the merged value/offaw projection (N=384).

template <int MODE>
__global__ __launch_bounds__(256) void gemm_bt(
    const __hip_bfloat16* __restrict__ A,
    const __hip_bfloat16* __restrict__ Bt,
    const int N, const int K,
    const float* __restrict__ bias0,
    const float* __restrict__ bias1,
    const float* __restrict__ bias2,
    void* C,
    void* extra,
    const void* extra2,
    const float* __restrict__ csum) {
    __shared__ __align__(16) __hip_bfloat16 As[2][128 * 32];
    __shared__ __align__(16) __hip_bfloat16 Bs[2][128 * 32];
    const int tid  = threadIdx.x;
    const int lane = tid & 63;
    const int wave = tid >> 6;
    const int wm = (wave >> 1) * 64;
    const int wn = (wave & 1) * 64;
    const int row0 = blockIdx.x * 128;
    const int col0 = blockIdx.y * 128;
    const int l15 = lane & 15;
    const int quad = lane >> 4;

    floatx4 acc[4][4] = {};

    const int sr = tid >> 2;
    const int sk = (tid & 3) * 8;

    const __hip_bfloat16* Ab = A + (size_t)row0 * K + sr * (size_t)K + sk;
    const __hip_bfloat16* Bb = Bt + (size_t)col0 * K + sr * (size_t)K + sk;
    const size_t half64 = (size_t)64 * K;

    auto stage = [&](int buf, int k0) {
#if HAS_GLL
        __builtin_amdgcn_global_load_lds(
            (const __attribute__((address_space(1))) void*)(Ab + k0),
            (__attribute__((address_space(3))) void*)(&As[buf][sr * 32 + sk]), 16, 0, 0);
        __builtin_amdgcn_global_load_lds(
            (const __attribute__((address_space(1))) void*)(Ab + half64 + k0),
            (__attribute__((address_space(3))) void*)(&As[buf][(sr + 64) * 32 + sk]), 16, 0, 0);
        __builtin_amdgcn_global_load_lds(
            (const __attribute__((address_space(1))) void*)(Bb + k0),
            (__attribute__((address_space(3))) void*)(&Bs[buf][sr * 32 + sk]), 16, 0, 0);
        __builtin_amdgcn_global_load_lds(
            (const __attribute__((address_space(1))) void*)(Bb + half64 + k0),
            (__attribute__((address_space(3))) void*)(&Bs[buf][(sr + 64) * 32 + sk]), 16, 0, 0);
#else
        *reinterpret_cast<uint4*>(&As[buf][sr * 32 + sk]) = *reinterpret_cast<const uint4*>(Ab + k0);
        *reinterpret_cast<uint4*>(&As[buf][(sr + 64) * 32 + sk]) = *reinterpret_cast<const uint4*>(Ab + half64 + k0);
        *reinterpret_cast<uint4*>(&Bs[buf][sr * 32 + sk]) = *reinterpret_cast<const uint4*>(Bb + k0);
        *reinterpret_cast<uint4*>(&Bs[buf][(sr + 64) * 32 + sk]) = *reinterpret_cast<const uint4*>(Bb + half64 + k0);
#endif
    };

    const int nk = K >> 5;
    stage(0, 0);
    for (int t = 0; t < nk; ++t) {
        __syncthreads();
        if (t + 1 < nk) stage((t + 1) & 1, (t + 1) * 32);
        const __hip_bfloat16* Asb = As[t & 1];
        const __hip_bfloat16* Bsb = Bs[t & 1];
        bf16x8 af[4], bfg[4];
#pragma unroll
        for (int i = 0; i < 4; ++i)
            af[i] = *reinterpret_cast<const bf16x8*>(&Asb[(wm + i * 16 + l15) * 32 + quad * 8]);
#pragma unroll
        for (int j = 0; j < 4; ++j)
            bfg[j] = *reinterpret_cast<const bf16x8*>(&Bsb[(wn + j * 16 + l15) * 32 + quad * 8]);
#pragma unroll
        for (int i = 0; i < 4; ++i)
#pragma unroll
            for (int j = 0; j < 4; ++j)
                acc[i][j] = __builtin_amdgcn_mfma_f32_16x16x32_bf16(af[i], bfg[j], acc[i][j], 0, 0, 0);
    }

#pragma unroll
    for (int i = 0; i < 4; ++i) {
#pragma unroll
        for (int j = 0; j < 4; ++j) {
#pragma unroll
            for (int rr = 0; rr < 4; ++rr) {
                int row = row0 + wm + i * 16 + quad * 4 + rr;
                int col = col0 + wn + j * 16 + l15;
                float v = acc[i][j][rr];
                if constexpr (MODE == MODE_BF16) {
                    v += bias0[col];
                    ((__hip_bfloat16*)C)[(size_t)row * N + col] = F2B(v);
                } else {  // MODE_VALOFFAW
                    if (col < 256) {
                        v += bias0[col];
                        ((__hip_bfloat16*)C)[(size_t)row * 256 + col] = F2B(v);
                    } else {
                        int c2 = col - 256;
                        const float* diag = (const float*)extra2;
                        v += (c2 < 96 ? bias1[c2] : bias2[c2 - 96]);
                        v += diag[row] * csum[c2];
                        ((__half*)extra)[(size_t)row * 128 + c2] = __float2half(v);
                    }
                }
            }
        }
    }
}

// ---------------- full-row GEMM + fused LayerNorm epilogue ----------------
// 512 threads, 8 waves (2 row-groups x 4 col-groups), 128x256 output per block
// -> block owns complete rows, so LN is computable in-block: per-quad 16-lane
// shfl partial sums -> 4 KB LDS partials -> barrier -> apply.
// REV=0: a2 = LN_a(xw + A@outT + b)          (attn buffer never materialized)
// REV=1: xres[tok] = x[tok] + A@projT + b (f32) AND hin[tok] = LN2(xres) (bf16)

template <int REV>
__global__ __launch_bounds__(512, 4) void gemm_row_ln(
    const __hip_bfloat16* __restrict__ A,     // M x 256 (window rows)
    const __hip_bfloat16* __restrict__ Bt,    // 256 x 256 (N,K)
    const float* __restrict__ bias,
    const __hip_bfloat16* __restrict__ xw,    // REV=0: residual bf16 (window rows)
    const float* __restrict__ xf,             // REV=1: original x f32 (token rows)
    const float* __restrict__ g, const float* __restrict__ b,
    __hip_bfloat16* __restrict__ obf,         // REV=0: a2 (window rows); REV=1: hin (token rows)
    float* __restrict__ of32) {               // REV=1: xres (token rows)
    __shared__ __align__(16) __hip_bfloat16 As[2][128 * 32];   // 16 KB
    __shared__ __align__(16) __hip_bfloat16 Bs[2][256 * 32];   // 32 KB
    __shared__ float p1[128 * 4], p2[128 * 4];                 // 4 KB partials
    const int tid  = threadIdx.x;
    const int lane = tid & 63;
    const int w    = tid >> 6;
    const int l15  = lane & 15;
    const int quad = lane >> 4;
    const int wm   = (w >> 2) * 64;
    const int wn   = (w & 3) * 64;
    const int wc   = w & 3;
    const int row0 = blockIdx.x * 128;

    const int sr = tid >> 2;
    const int sk = (tid & 3) * 8;
    const __hip_bfloat16* Ab = A + (size_t)(row0 + sr) * 256 + sk;
    const __hip_bfloat16* Bb = Bt + (size_t)sr * 256 + sk;

    floatx4 acc[4][4] = {};

    auto stage = [&](int buf, int k0) {
#if HAS_GLL
        __builtin_amdgcn_global_load_lds(
            (const __attribute__((address_space(1))) void*)(Ab + k0),
            (__attribute__((address_space(3))) void*)(&As[buf][sr * 32 + sk]), 16, 0, 0);
        __builtin_amdgcn_global_load_lds(
            (const __attribute__((address_space(1))) void*)(Bb + k0),
            (__attribute__((address_space(3))) void*)(&Bs[buf][sr * 32 + sk]), 16, 0, 0);
        __builtin_amdgcn_global_load_lds(
            (const __attribute__((address_space(1))) void*)(Bb + (size_t)128 * 256 + k0),
            (__attribute__((address_space(3))) void*)(&Bs[buf][(sr + 128) * 32 + sk]), 16, 0, 0);
#else
        *reinterpret_cast<uint4*>(&As[buf][sr * 32 + sk]) = *reinterpret_cast<const uint4*>(Ab + k0);
        *reinterpret_cast<uint4*>(&Bs[buf][sr * 32 + sk]) = *reinterpret_cast<const uint4*>(Bb + k0);
        *reinterpret_cast<uint4*>(&Bs[buf][(sr + 128) * 32 + sk]) = *reinterpret_cast<const uint4*>(Bb + (size_t)128 * 256 + k0);
#endif
    };

    stage(0, 0);
    for (int t = 0; t < 8; ++t) {
        __syncthreads();
        if (t + 1 < 8) stage((t + 1) & 1, (t + 1) * 32);
        const __hip_bfloat16* Asb = As[t & 1];
        const __hip_bfloat16* Bsb = Bs[t & 1];
        bf16x8 af[4], bfg[4];
#pragma unroll
        for (int i = 0; i < 4; ++i)
            af[i] = *reinterpret_cast<const bf16x8*>(&Asb[(wm + i * 16 + l15) * 32 + quad * 8]);
#pragma unroll
        for (int j = 0; j < 4; ++j)
            bfg[j] = *reinterpret_cast<const bf16x8*>(&Bsb[(wn + j * 16 + l15) * 32 + quad * 8]);
#pragma unroll
        for (int i = 0; i < 4; ++i)
#pragma unroll
            for (int j = 0; j < 4; ++j)
                acc[i][j] = __builtin_amdgcn_mfma_f32_16x16x32_bf16(af[i], bfg[j], acc[i][j], 0, 0, 0);
    }

    // hoisted per-column constants (col = wn + j*16 + l15)
    float biasj[4], gj[4], bj[4];
#pragma unroll
    for (int j = 0; j < 4; ++j) {
        int col = wn + j * 16 + l15;
        biasj[j] = bias[col];
        gj[j] = g[col];
        bj[j] = b[col];
    }

    // pass 1: finalize v (bias + residual), write xres (REV), accumulate row partials
#pragma unroll
    for (int i = 0; i < 4; ++i) {
#pragma unroll
        for (int rr = 0; rr < 4; ++rr) {
            int lrow = wm + i * 16 + quad * 4 + rr;
            int grow = row0 + lrow;
            int tok = 0;
            if (REV) win_decode(grow, tok);
            float s1 = 0.f, s2 = 0.f;
#pragma unroll
            for (int j = 0; j < 4; ++j) {
                int col = wn + j * 16 + l15;
                float v = acc[i][j][rr] + biasj[j];
                if constexpr (REV == 0) {
                    v += B2F(xw[(size_t)grow * 256 + col]);
                } else {
                    v += xf[(size_t)tok * 256 + col];
                    of32[(size_t)tok * 256 + col] = v;
                }
                acc[i][j][rr] = v;
                s1 += v;
                s2 += v * v;
            }
#pragma unroll
            for (int off = 1; off < 16; off <<= 1) {
                s1 += __shfl_xor(s1, off, 64);
                s2 += __shfl_xor(s2, off, 64);
            }
            if (l15 == 0) {
                p1[lrow * 4 + wc] = s1;
                p2[lrow * 4 + wc] = s2;
            }
        }
    }
    __syncthreads();

    // pass 2: apply LN, write bf16 output
#pragma unroll
    for (int i = 0; i < 4; ++i) {
#pragma unroll
        for (int rr = 0; rr < 4; ++rr) {
            int lrow = wm + i * 16 + quad * 4 + rr;
            int grow = row0 + lrow;
            int tok = 0;
            if (REV) win_decode(grow, tok);
            float t1 = p1[lrow * 4 + 0] + p1[lrow * 4 + 1] + p1[lrow * 4 + 2] + p1[lrow * 4 + 3];
            float t2 = p2[lrow * 4 + 0] + p2[lrow * 4 + 1] + p2[lrow * 4 + 2] + p2[lrow * 4 + 3];
            float mean = t1 * (1.f / 256.f);
            float var = t2 * (1.f / 256.f) - mean * mean;
            float rstd = rsqrtf(var + 1e-5f);
            size_t orow = REV ? (size_t)tok : (size_t)grow;
#pragma unroll
            for (int j = 0; j < 4; ++j) {
                int col = wn + j * 16 + l15;
                float o = (acc[i][j][rr] - mean) * rstd * gj[j] + bj[j];
                obf[orow * 256 + col] = F2B(o);
            }
        }
    }
}

// ---------------- fused MLP (round-6 version, measured 150 us) ----------------

__global__ __launch_bounds__(512, 4) void mlp_fused(
    const __hip_bfloat16* __restrict__ hin,   // M x 256
    const __hip_bfloat16* __restrict__ fc1T,  // 1024 x 256 (N,K)
    const __hip_bfloat16* __restrict__ fc2T,  // 256 x 1024 (N,K)
    const float* __restrict__ fc1_b, const float* __restrict__ fc2_b,
    float* __restrict__ out) {                // M x 256 f32, in-place xres+=mlp
    __shared__ __align__(16) __hip_bfloat16 hs[8 * 128 * 32];  // 64 KB: hin as 8 ktiles [128][32]
    __shared__ __align__(16) __hip_bfloat16 as[2 * 128 * 32];  // 16 KB: act as 2 ktiles [128][32]
    const int tid  = threadIdx.x;
    const int lane = tid & 63;
    const int w    = tid >> 6;
    const int r0   = blockIdx.x * 128;
    const int l15  = lane & 15;
    const int quad = lane >> 4;
    const int wm   = (w >> 2) * 64;   // row group (0/64)
    const int wn   = (w & 3) * 64;    // out col group
    const int ac   = (w & 3) * 16;    // act col group within 64

    // stage hin rows [r0, r0+128) as 8 ktiles of [128][32] (lane-linear dest)
    {
        const int row = tid >> 2, ke = (tid & 3) * 8;
#if HAS_GLL
#pragma unroll
        for (int kt = 0; kt < 8; ++kt)
            __builtin_amdgcn_global_load_lds(
                (const __attribute__((address_space(1))) void*)(hin + (size_t)(r0 + row) * 256 + kt * 32 + ke),
                (__attribute__((address_space(3))) void*)(&hs[kt * 4096 + row * 32 + ke]), 16, 0, 0);
#else
#pragma unroll
        for (int kt = 0; kt < 8; ++kt)
            *(uint4*)(&hs[kt * 4096 + row * 32 + ke]) =
                *(const uint4*)(hin + (size_t)(r0 + row) * 256 + kt * 32 + ke);
#endif
    }
    floatx4 acc[4][4] = {};
    const int kt2 = (ac + l15) >> 5, ko = (ac + l15) & 31;   // act LDS write coords
    __syncthreads();

    for (int kk = 0; kk < 1024; kk += 64) {
        // ---- phase 1: act = gelu(hs @ fc1T[:, kk..kk+64) + b1), this wave's 16 cols ----
        floatx4 pa[4] = {};
#pragma unroll
        for (int ks = 0; ks < 8; ++ks) {
            bf16x8 b1 = *(const bf16x8*)(fc1T + (size_t)(kk + ac + l15) * 256 + ks * 32 + quad * 8);
#pragma unroll
            for (int i = 0; i < 4; ++i) {
                bf16x8 a = *(const bf16x8*)(&hs[ks * 4096 + (wm + i * 16 + l15) * 32 + quad * 8]);
                pa[i] = __builtin_amdgcn_mfma_f32_16x16x32_bf16(a, b1, pa[i], 0, 0, 0);
            }
        }
        float bb = fc1_b[kk + ac + l15];
        __syncthreads();   // prev phase-2 reads of `as` complete
#pragma unroll
        for (int i = 0; i < 4; ++i) {
#pragma unroll
            for (int rr = 0; rr < 4; ++rr) {
                float v = pa[i][rr] + bb;
                float t2 = 1.5957691216057308f * (v + 0.044715f * v * v * v);
                v = v / (1.f + __expf(-t2));
                int row = wm + i * 16 + quad * 4 + rr;
                as[kt2 * 4096 + row * 32 + ko] = F2B(v);
            }
        }
        __syncthreads();   // `as` ready
        // ---- phase 2: acc += act @ fc2T[:, kk..kk+64)^T (transient B loads) ----
#pragma unroll
        for (int ks = 0; ks < 2; ++ks) {
            bf16x8 a4[4];
#pragma unroll
            for (int i = 0; i < 4; ++i)
                a4[i] = *(const bf16x8*)(&as[ks * 4096 + (wm + i * 16 + l15) * 32 + quad * 8]);
#pragma unroll
            for (int j = 0; j < 4; ++j) {
                bf16x8 b2 = *(const bf16x8*)(fc2T + (size_t)(wn + j * 16 + l15) * 1024 + kk + ks * 32 + quad * 8);
#pragma unroll
                for (int i = 0; i < 4; ++i)
                    acc[i][j] = __builtin_amdgcn_mfma_f32_16x16x32_bf16(a4[i], b2, acc[i][j], 0, 0, 0);
            }
        }
    }
    // epilogue: out += acc + fc2_b (f32 in-place residual)
#pragma unroll
    for (int i = 0; i < 4; ++i)
#pragma unroll
        for (int j = 0; j < 4; ++j)
#pragma unroll
            for (int rr = 0; rr < 4; ++rr) {
                int row = r0 + wm + i * 16 + quad * 4 + rr;
                int col = wn + j * 16 + l15;
                out[(size_t)row * 256 + col] += acc[i][j][rr] + fc2_b[col];
            }
}

// ---------------- host launcher ----------------

extern "C" void kernel_launch(void* const* d_in, const int* in_sizes, int n_in,
                              void* d_out, int out_size, void* d_ws, size_t ws_size,
                              hipStream_t stream) {
    const float* x      = (const float*)d_in[0];
    const float* mask   = (const float*)d_in[1];
    const float* n1g    = (const float*)d_in[2];
    const float* n1b    = (const float*)d_in[3];
    const float* val_w  = (const float*)d_in[4];
    const float* val_b  = (const float*)d_in[5];
    const float* off_w  = (const float*)d_in[6];
    const float* off_b  = (const float*)d_in[7];
    const float* aw_w   = (const float*)d_in[8];
    const float* aw_b   = (const float*)d_in[9];
    const float* out_w  = (const float*)d_in[10];
    const float* out_b  = (const float*)d_in[11];
    const float* ang    = (const float*)d_in[12];
    const float* anb    = (const float*)d_in[13];
    const float* proj_w = (const float*)d_in[14];
    const float* proj_b = (const float*)d_in[15];
    const float* n2g    = (const float*)d_in[16];
    const float* n2b    = (const float*)d_in[17];
    const float* fc1_w  = (const float*)d_in[18];
    const float* fc1_b  = (const float*)d_in[19];
    const float* fc2_w  = (const float*)d_in[20];
    const float* fc2_b  = (const float*)d_in[21];

    char* ws = (char*)d_ws;
    size_t o = 0;
    auto alloc = [&](size_t bytes) {
        size_t r = o;
        o += (bytes + 255) & ~(size_t)255;
        return r;
    };
    const size_t M = MROWS;
    const size_t REGION_B = M * 128 * 2 + M * 256 * 2;                 // offaw + ai

    __hip_bfloat16* valT    = (__hip_bfloat16*)(ws + alloc(256 * 256 * 2));
    __hip_bfloat16* offawT  = (__hip_bfloat16*)(ws + alloc(128 * 256 * 2));
    __hip_bfloat16* outT    = (__hip_bfloat16*)(ws + alloc(256 * 256 * 2));
    __hip_bfloat16* projT   = (__hip_bfloat16*)(ws + alloc(256 * 256 * 2));
    __hip_bfloat16* fc1T    = (__hip_bfloat16*)(ws + alloc(1024 * 256 * 2));
    __hip_bfloat16* fc2T    = (__hip_bfloat16*)(ws + alloc(256 * 1024 * 2));
    float*          csum    = (float*)(ws + alloc(128 * 4));
    float*          diag    = (float*)(ws + alloc(M * 4));
    char*           slab1   = ws + alloc(M * 256 * 2);                 // xw -> a2
    char*           region  = ws + alloc(REGION_B);                    // multi-use
    (void)ws_size; (void)in_sizes; (void)n_in; (void)out_size;

    __hip_bfloat16* xw    = (__hip_bfloat16*)slab1;
    __hip_bfloat16* a2    = (__hip_bfloat16*)slab1;
    __half*         offaw = (__half*)region;                           // M x 128 f16
    __hip_bfloat16* ai    = (__hip_bfloat16*)(region + M * 128 * 2);   // M x 256 bf16
    __hip_bfloat16* hin   = (__hip_bfloat16*)region;                   // M x 256 bf16 (offaw/ai dead)
    __hip_bfloat16* value = (__hip_bfloat16*)d_out;                    // bf16 scratch
    float*          xres  = (float*)d_out;                             // f32 trunk

    dim3 blk(256);
    // 0. fused front: transposes + diag + csum + LN1 (16 rows/block)
    hipLaunchKernelGGL(fused_pre, dim3(2944 + 196 + 1 + MROWS / 16), blk, 0, stream,
                       x, n1g, n1b, xw, mask, diag, csum,
                       val_w, off_w, aw_w, out_w, proj_w, fc1_w, fc2_w,
                       valT, offawT, outT, projT, fc1T, fc2T);
    // 2+3 merged. N=384 over [valT|offawT]: value -> d_out bf16, offaw -> region f16
    hipLaunchKernelGGL((gemm_bt<MODE_VALOFFAW>), dim3(MROWS / 128, 3), blk, 0, stream,
                       xw, valT, 384, 256, val_b, off_b, aw_b,
                       (void*)value, (void*)offaw, (const void*)diag, csum);
    // 4. ai = fully-LDS-staged prep + gather sample(value)
    hipLaunchKernelGGL(sample_fused, dim3(MROWS / 98), dim3(512), 0, stream,
                       offaw, value, ai);
    // 5+6. a2 = LN_a(xw + ai@outT + out_b)   (full-row blocks; attn never materialized;
    //      in-block barrier orders all xw reads before a2 writes in slab1)
    hipLaunchKernelGGL((gemm_row_ln<0>), dim3(MROWS / 128), dim3(512), 0, stream,
                       ai, outT, out_b, xw, (const float*)nullptr, ang, anb,
                       a2, (float*)nullptr);
    // 7+8. xres = x + reverse(a2@projT + b) (f32, d_out) AND hin = LN2(xres) (region)
    hipLaunchKernelGGL((gemm_row_ln<1>), dim3(MROWS / 128), dim3(512), 0, stream,
                       a2, projT, proj_b, (const __hip_bfloat16*)nullptr, x, n2g, n2b,
                       hin, xres);
    // 9. fused MLP: out = xres + gelu(hin@fc1+b1)@fc2 + b2, in-place on d_out
    hipLaunchKernelGGL(mlp_fused, dim3(MROWS / 128), dim3(512), 0, stream,
                       hin, fc1T, fc2T, fc1_b, fc2_b, (float*)d_out);
}